// Round 1
// baseline (4074.218 us; speedup 1.0000x reference)
//
#include <hip/hip_runtime.h>
#include <cstdint>
#include <cstddef>

#define NLAYERS 19
#define NB 4
#define RES_C 128
#define DIL2 256
#define SKIPC 256
#define INC 60
#define CONDC 80
#define OUTC 240
#define T_IN 6144
#define T0LEN 6135   // after start conv (K=10, VALID)
#define T_FIN 4601
#define TILE 64
#define BLK 512

#if __has_builtin(__builtin_amdgcn_exp2f)
#define EXP2F(x) __builtin_amdgcn_exp2f(x)
#else
#define EXP2F(x) exp2f(x)
#endif
#if __has_builtin(__builtin_amdgcn_rcpf)
#define RCPF(x) __builtin_amdgcn_rcpf(x)
#else
#define RCPF(x) (1.0f/(x))
#endif

__device__ __forceinline__ float fexp(float x){ return EXP2F(x * 1.4426950408889634f); }
__device__ __forceinline__ float fsigmoid(float x){ return RCPF(1.0f + fexp(-x)); }
__device__ __forceinline__ float ftanh(float x){ return 1.0f - 2.0f * RCPF(1.0f + fexp(2.0f*x)); }

// ---------------------------------------------------------------------------
// condi[i][b][o] = cond_b[i][o] + sum_c cond_w[i][o][c] * cond[b][c]
// cend[b][o]    = cend_b[o]    + sum_c cend_w[o][c]   * cond[b][c]
__global__ void cond_kernel(const float* __restrict__ cond,
                            const float* __restrict__ cond_w, const float* __restrict__ cond_b,
                            const float* __restrict__ cend_w, const float* __restrict__ cend_b,
                            float* __restrict__ condi, float* __restrict__ cend){
  int blk = blockIdx.x; int o = threadIdx.x;  // 256 threads
  if (blk < NLAYERS*NB) {
    int i = blk / NB, b = blk % NB;
    float acc = cond_b[i*DIL2 + o];
    const float* w = cond_w + (size_t)(i*DIL2 + o)*CONDC;
    const float* cv = cond + b*CONDC;
    for (int c = 0; c < CONDC; ++c) acc += w[c]*cv[c];
    condi[(size_t)blk*DIL2 + o] = acc;
  } else {
    int b = blk - NLAYERS*NB;
    float acc = cend_b[o];
    const float* w = cend_w + (size_t)o*CONDC;
    const float* cv = cond + b*CONDC;
    for (int c = 0; c < CONDC; ++c) acc += w[c]*cv[c];
    cend[b*SKIPC + o] = acc;
  }
}

// ---------------------------------------------------------------------------
// start conv: x[b][oc][t] = b[oc] + sum_{c<60,k<10} w[oc][c][k] * in[b][c][t+k]
__global__ __launch_bounds__(BLK) void start_kernel(const float* __restrict__ in,
                                                    const float* __restrict__ w,
                                                    const float* __restrict__ bias,
                                                    float* __restrict__ xout){
  __shared__ float lin[INC*73];
  int b = blockIdx.y; int t0 = blockIdx.x * TILE;
  for (int e = threadIdx.x; e < INC*73; e += BLK){
    int c = e / 73, tt = e % 73; int gt = t0 + tt;
    lin[e] = (gt < T_IN) ? in[(size_t)(b*INC + c)*T_IN + gt] : 0.f;
  }
  __syncthreads();
  int t = threadIdx.x & 63;
  int wave = __builtin_amdgcn_readfirstlane((int)(threadIdx.x >> 6));
  int gt = t0 + t;
  for (int g = 0; g < 2; ++g){
    int oc0 = wave*16 + g*8;
    float acc[8];
    #pragma unroll
    for (int j=0;j<8;++j) acc[j] = bias[oc0+j];
    for (int c = 0; c < INC; ++c){
      #pragma unroll
      for (int k = 0; k < 10; ++k){
        float v = lin[c*73 + t + k];
        #pragma unroll
        for (int j=0;j<8;++j) acc[j] += w[((oc0+j)*INC + c)*10 + k] * v;
      }
    }
    if (gt < T0LEN){
      #pragma unroll
      for (int j=0;j<8;++j) xout[(size_t)(b*RES_C + oc0+j)*T_IN + gt] = acc[j];
    }
  }
}

// ---------------------------------------------------------------------------
// One WaveNet layer, fully fused:
//   f/g = dil_w *{t, t+d} x + dil_b + condi ; z = tanh(f)*sigmoid(g)
//   skip[trailing 4601] (+)= skip_w @ z + skip_b
//   xout = res_w @ z + res_b + x[t+d]          (skipped on last layer)
__global__ __launch_bounds__(BLK) void layer_kernel(const float* __restrict__ xin, float* __restrict__ xout,
     float* __restrict__ skip,
     const float* __restrict__ dil_w, const float* __restrict__ dil_b,
     const float* __restrict__ res_w, const float* __restrict__ res_b,
     const float* __restrict__ skip_w, const float* __restrict__ skip_b,
     const float* __restrict__ condi,
     int layer, int d, int Tin, int Tout, int first, int last){
  __shared__ float lx0[RES_C*TILE];  // x[t] tile, later reused to hold z
  __shared__ float lx1[RES_C*TILE];  // x[t+d] tile (also residual source)
  int b = blockIdx.y; int t0 = blockIdx.x*TILE;
  for (int e = threadIdx.x; e < RES_C*TILE; e += BLK){
    int c = e >> 6, tt = e & 63; int gt = t0 + tt;
    size_t base = (size_t)(b*RES_C + c)*T_IN;
    lx0[e] = (gt < Tin)     ? xin[base + gt]     : 0.f;
    lx1[e] = (gt + d < Tin) ? xin[base + gt + d] : 0.f;
  }
  __syncthreads();
  int t = threadIdx.x & 63;
  int wave = __builtin_amdgcn_readfirstlane((int)(threadIdx.x >> 6));
  const float* wb = dil_w + (size_t)layer*DIL2*RES_C*2;
  const float* cb = condi + (size_t)(layer*NB + b)*DIL2;
  const float* db = dil_b + (size_t)layer*DIL2;

  float z[16];
  for (int g = 0; g < 2; ++g){
    int zc0 = wave*16 + g*8;
    float accf[8], accg[8];
    #pragma unroll
    for (int j=0;j<8;++j){
      accf[j] = db[zc0+j]     + cb[zc0+j];
      accg[j] = db[zc0+j+128] + cb[zc0+j+128];
    }
    for (int cc = 0; cc < RES_C; ++cc){
      float xv0 = lx0[cc*64 + t], xv1 = lx1[cc*64 + t];
      #pragma unroll
      for (int j=0;j<8;++j){
        const float* wf = wb + ((zc0+j)*RES_C + cc)*2;
        const float* wg = wb + ((zc0+j+128)*RES_C + cc)*2;
        accf[j] += wf[0]*xv0 + wf[1]*xv1;
        accg[j] += wg[0]*xv0 + wg[1]*xv1;
      }
    }
    #pragma unroll
    for (int j=0;j<8;++j) z[g*8+j] = ftanh(accf[j]) * fsigmoid(accg[j]);
  }
  __syncthreads();          // everyone done READING lx0
  {
    int zc0 = wave*16;
    #pragma unroll
    for (int j=0;j<16;++j) lx0[(zc0+j)*64 + t] = z[j];
  }
  __syncthreads();          // z visible to all

  int gt = t0 + t;
  bool valid = gt < Tout;

  if (!last){
    int rc0 = wave*16;
    for (int g=0; g<2; ++g){
      float acc[8];
      #pragma unroll
      for (int j=0;j<8;++j) acc[j] = res_b[layer*RES_C + rc0+g*8+j];
      for (int cc=0; cc<RES_C; ++cc){
        float zv = lx0[cc*64+t];
        #pragma unroll
        for (int j=0;j<8;++j)
          acc[j] += res_w[((size_t)layer*RES_C + rc0+g*8+j)*RES_C + cc] * zv;
      }
      if (valid){
        #pragma unroll
        for (int j=0;j<8;++j){
          int rc = rc0+g*8+j;
          xout[(size_t)(b*RES_C+rc)*T_IN + gt] = acc[j] + lx1[rc*64+t];
        }
      }
    }
  }

  int tw = gt - (Tout - T_FIN);
  bool sval = valid && (tw >= 0);
  int sc0 = wave*32;
  for (int g=0; g<4; ++g){
    float acc[8];
    #pragma unroll
    for (int j=0;j<8;++j) acc[j] = skip_b[layer*DIL2 + sc0+g*8+j];
    for (int cc=0; cc<RES_C; ++cc){
      float zv = lx0[cc*64+t];
      #pragma unroll
      for (int j=0;j<8;++j)
        acc[j] += skip_w[((size_t)layer*DIL2 + sc0+g*8+j)*RES_C + cc] * zv;
    }
    if (sval){
      #pragma unroll
      for (int j=0;j<8;++j){
        size_t si = (size_t)(b*SKIPC + sc0+g*8+j)*T_FIN + tw;
        skip[si] = (first ? 0.f : skip[si]) + acc[j];
      }
    }
  }
}

// ---------------------------------------------------------------------------
// out[b][oc][t] = sigmoid( end_b[oc] + sum_s end_w[oc][s] * tanh(skip[b][s][t] + cend[b][s]) )
__global__ __launch_bounds__(BLK) void final_kernel(const float* __restrict__ skip,
    const float* __restrict__ cend,
    const float* __restrict__ end_w, const float* __restrict__ end_b,
    float* __restrict__ out){
  __shared__ float st[SKIPC*TILE];
  int b = blockIdx.y; int t0 = blockIdx.x*TILE;
  for (int e = threadIdx.x; e < SKIPC*TILE; e += BLK){
    int c = e >> 6, tt = e & 63; int gt = t0+tt;
    float v = 0.f;
    if (gt < T_FIN) v = ftanh(skip[(size_t)(b*SKIPC+c)*T_FIN + gt] + cend[b*SKIPC+c]);
    st[e] = v;
  }
  __syncthreads();
  int t = threadIdx.x & 63;
  int wave = __builtin_amdgcn_readfirstlane((int)(threadIdx.x >> 6));
  int gt = t0+t;
  int oc0 = wave*30;
  for (int g=0; g<5; ++g){
    float acc[6];
    #pragma unroll
    for (int j=0;j<6;++j) acc[j] = end_b[oc0+g*6+j];
    for (int cc=0; cc<SKIPC; ++cc){
      float zv = st[cc*64+t];
      #pragma unroll
      for (int j=0;j<6;++j) acc[j] += end_w[(size_t)(oc0+g*6+j)*SKIPC + cc]*zv;
    }
    if (gt < T_FIN){
      #pragma unroll
      for (int j=0;j<6;++j) out[(size_t)(b*OUTC + oc0+g*6+j)*T_FIN + gt] = fsigmoid(acc[j]);
    }
  }
}

// ---------------------------------------------------------------------------
extern "C" void kernel_launch(void* const* d_in, const int* in_sizes, int n_in,
                              void* d_out, int out_size, void* d_ws, size_t ws_size,
                              hipStream_t stream){
  const float* input     = (const float*)d_in[0];
  const float* condition = (const float*)d_in[1];
  const float* start_w   = (const float*)d_in[2];
  const float* start_b   = (const float*)d_in[3];
  const float* dil_w     = (const float*)d_in[4];
  const float* dil_b     = (const float*)d_in[5];
  const float* cond_w    = (const float*)d_in[6];
  const float* cond_b    = (const float*)d_in[7];
  const float* res_w     = (const float*)d_in[8];
  const float* res_b     = (const float*)d_in[9];
  const float* skip_w    = (const float*)d_in[10];
  const float* skip_b    = (const float*)d_in[11];
  const float* end_w     = (const float*)d_in[12];
  const float* end_b     = (const float*)d_in[13];
  const float* cend_w    = (const float*)d_in[14];
  const float* cend_b    = (const float*)d_in[15];
  float* out = (float*)d_out;

  char* ws = (char*)d_ws;
  size_t xbytes = (size_t)NB*RES_C*T_IN*sizeof(float);       // 12.58 MB
  size_t sbytes = (size_t)NB*SKIPC*T_FIN*sizeof(float);      // 18.85 MB
  float* xA    = (float*)ws;
  float* xB    = (float*)(ws + xbytes);
  float* skip  = (float*)(ws + 2*xbytes);
  float* condi = (float*)(ws + 2*xbytes + sbytes);
  float* cend  = condi + (size_t)NLAYERS*NB*DIL2;

  cond_kernel<<<NLAYERS*NB + NB, 256, 0, stream>>>(condition, cond_w, cond_b, cend_w, cend_b, condi, cend);

  {
    dim3 grid((T0LEN + TILE - 1)/TILE, NB);
    start_kernel<<<grid, BLK, 0, stream>>>(input, start_w, start_b, xA);
  }

  int dils[NLAYERS]; int n = 0;
  for (int bb = 0; bb < 2; ++bb){ int nn = (bb==0) ? 10 : 9; for (int k = 0; k < nn; ++k) dils[n++] = 1<<k; }

  float* xin = xA; float* xo = xB;
  int Tin = T0LEN;
  for (int i = 0; i < NLAYERS; ++i){
    int d = dils[i]; int Tout = Tin - d;
    dim3 grid((Tout + TILE - 1)/TILE, NB);
    layer_kernel<<<grid, BLK, 0, stream>>>(xin, xo, skip, dil_w, dil_b, res_w, res_b, skip_w, skip_b,
                                           condi, i, d, Tin, Tout, (i==0)?1:0, (i==NLAYERS-1)?1:0);
    float* tmp = xin; xin = xo; xo = tmp;
    Tin = Tout;
  }

  {
    dim3 grid((T_FIN + TILE - 1)/TILE, NB);
    final_kernel<<<grid, BLK, 0, stream>>>(skip, cend, end_w, end_b, out);
  }
}

// Round 2
// 952.592 us; speedup vs baseline: 4.2770x; 4.2770x over previous
//
#include <hip/hip_runtime.h>
#include <cstdint>
#include <cstddef>

#define NLAYERS 19
#define NB 4
#define RES_C 128
#define DIL2 256
#define SKIPC 256
#define INC 60
#define CONDC 80
#define OUTC 240
#define T_IN 6144
#define T0LEN 6135   // after start conv (K=10, VALID)
#define T_FIN 4601
#define TILE 64
#define BLK 512

#define NDIL (NLAYERS*256*256)
#define NSKP (NLAYERS*256*128)
#define NRES (NLAYERS*128*128)
#define NEND (256*256)

typedef short bf16x8 __attribute__((ext_vector_type(8)));
typedef float f32x4 __attribute__((ext_vector_type(4)));

#if __has_builtin(__builtin_amdgcn_exp2f)
#define EXP2F(x) __builtin_amdgcn_exp2f(x)
#else
#define EXP2F(x) exp2f(x)
#endif
#if __has_builtin(__builtin_amdgcn_rcpf)
#define RCPF(x) __builtin_amdgcn_rcpf(x)
#else
#define RCPF(x) (1.0f/(x))
#endif

__device__ __forceinline__ float fexp(float x){ return EXP2F(x * 1.4426950408889634f); }
__device__ __forceinline__ float fsigmoid(float x){ return RCPF(1.0f + fexp(-x)); }
__device__ __forceinline__ float ftanh(float x){ return 1.0f - 2.0f * RCPF(1.0f + fexp(2.0f*x)); }

__device__ __forceinline__ unsigned short f2bf(float f){
  unsigned u = __builtin_bit_cast(unsigned, f);
  u = u + 0x7FFFu + ((u >> 16) & 1u);   // RNE (finite values only)
  return (unsigned short)(u >> 16);
}

// ---------------------------------------------------------------------------
// Pack weights to bf16. dilWb rows interleaved: m even=filter ch m/2, m odd=gate ch m/2.
// K order: k<128 -> tap0 (x[t]) channel k ; k>=128 -> tap1 (x[t+d]) channel k-128.
__global__ void prep_weights(const float* __restrict__ dil_w, const float* __restrict__ skip_w,
                             const float* __restrict__ res_w, const float* __restrict__ end_w,
                             unsigned short* __restrict__ dilWb, unsigned short* __restrict__ skipWb,
                             unsigned short* __restrict__ resWb, unsigned short* __restrict__ endWb){
  const int total = NDIL + NSKP + NRES + NEND;
  for (int idx = blockIdx.x*256 + threadIdx.x; idx < total; idx += gridDim.x*256){
    if (idx < NDIL){
      int l = idx >> 16; int rem = idx & 65535; int m = rem >> 8; int k = rem & 255;
      int o = ((m & 1) << 7) + (m >> 1); int c = k & 127; int tap = k >> 7;
      dilWb[idx] = f2bf(dil_w[(((size_t)l*256 + o)*128 + c)*2 + tap]);
    } else if (idx < NDIL + NSKP){
      int j = idx - NDIL;
      skipWb[j] = f2bf(skip_w[j]);           // [l][m][k] identical layout
    } else if (idx < NDIL + NSKP + NRES){
      int j = idx - NDIL - NSKP;
      resWb[j] = f2bf(res_w[j]);             // [l][m][k] identical layout
    } else {
      int j = idx - NDIL - NSKP - NRES;
      int m = j >> 8; int k = j & 255;
      endWb[j] = (m < OUTC) ? f2bf(end_w[(size_t)m*256 + k]) : 0;
    }
  }
}

// ---------------------------------------------------------------------------
// cbias[l][b][m] = dil_b[o(m)] + cond_b[l][o(m)] + sum_c cond_w[l][o(m)][c]*cond[b][c]
// cend[b][s]    = cend_b[s] + sum_c cend_w[s][c]*cond[b][c]
__global__ void prep_bias(const float* __restrict__ cond, const float* __restrict__ dil_b,
                          const float* __restrict__ cond_w, const float* __restrict__ cond_b,
                          const float* __restrict__ cend_w, const float* __restrict__ cend_b,
                          float* __restrict__ cbias, float* __restrict__ cend){
  int blk = blockIdx.x; int m = threadIdx.x;
  if (blk < NLAYERS*NB){
    int l = blk >> 2, b = blk & 3;
    int o = ((m & 1) << 7) + (m >> 1);
    float acc = dil_b[l*256 + o] + cond_b[l*256 + o];
    const float* w = cond_w + ((size_t)l*256 + o)*CONDC;
    const float* cv = cond + b*CONDC;
    for (int c = 0; c < CONDC; ++c) acc += w[c]*cv[c];
    cbias[((size_t)l*NB + b)*256 + m] = acc;
  } else {
    int b = blk - NLAYERS*NB;
    float acc = cend_b[m];
    const float* w = cend_w + (size_t)m*CONDC;
    const float* cv = cond + b*CONDC;
    for (int c = 0; c < CONDC; ++c) acc += w[c]*cv[c];
    cend[b*256 + m] = acc;
  }
}

// ---------------------------------------------------------------------------
// start conv (fp32 VALU): x[b][oc][t] = b[oc] + sum_{c<60,k<10} w[oc][c][k]*in[b][c][t+k]
__global__ __launch_bounds__(BLK) void start_kernel(const float* __restrict__ in,
                                                    const float* __restrict__ w,
                                                    const float* __restrict__ bias,
                                                    float* __restrict__ xout){
  __shared__ float lin[INC*73];
  int b = blockIdx.y; int t0 = blockIdx.x * TILE;
  for (int e = threadIdx.x; e < INC*73; e += BLK){
    int c = e / 73, tt = e % 73; int gt = t0 + tt;
    lin[e] = (gt < T_IN) ? in[(size_t)(b*INC + c)*T_IN + gt] : 0.f;
  }
  __syncthreads();
  int t = threadIdx.x & 63;
  int wave = __builtin_amdgcn_readfirstlane((int)(threadIdx.x >> 6));
  int gt = t0 + t;
  for (int g = 0; g < 2; ++g){
    int oc0 = wave*16 + g*8;
    float acc[8];
    #pragma unroll
    for (int j=0;j<8;++j) acc[j] = bias[oc0+j];
    for (int c = 0; c < INC; ++c){
      #pragma unroll
      for (int k = 0; k < 10; ++k){
        float v = lin[c*73 + t + k];
        #pragma unroll
        for (int j=0;j<8;++j) acc[j] += w[((oc0+j)*INC + c)*10 + k] * v;
      }
    }
    if (gt < T0LEN){
      #pragma unroll
      for (int j=0;j<8;++j) xout[(size_t)(b*RES_C + oc0+j)*T_IN + gt] = acc[j];
    }
  }
}

// ---------------------------------------------------------------------------
// Fused MFMA layer. x fp32 in global; B operands bf16 in swizzled LDS.
__global__ __launch_bounds__(BLK) void layer_mfma(
    const float* __restrict__ xin, float* __restrict__ xout, float* __restrict__ skip,
    const unsigned short* __restrict__ dilWb, const unsigned short* __restrict__ skipWb,
    const unsigned short* __restrict__ resWb, const float* __restrict__ cbias,
    const float* __restrict__ skip_b, const float* __restrict__ res_b,
    int layer, int d, int Tin, int Tout, int first, int last){
  __shared__ char Bx[64*512];   // [t][k:256] bf16, 16B slots swizzled: slot^= (t&31)
  __shared__ char Bz[64*256];   // [t][ch:128] bf16, slot ^= (t&15)
  const int tid = threadIdx.x;
  const int b = blockIdx.y; const int t0 = blockIdx.x*TILE;
  const int lane = tid & 63;
  const int wave = __builtin_amdgcn_readfirstlane(tid >> 6);
  const int q = lane >> 4;          // 0..3
  const int r16 = lane & 15;        // row-in-Afrag / col-in-Bfrag

  // ---- stage Bx: k<128 = x[t] ch k ; k>=128 = x[t+d] ch k-128
  {
    const int t = lane;
    const int gt = t0 + t;
    #pragma unroll
    for (int i = 0; i < 32; i += 2){
      int k0 = wave*32 + i;
      int tap = k0 >> 7; int c = k0 & 127;
      int gtt = gt + (tap ? d : 0);
      float v0 = 0.f, v1 = 0.f;
      if (gtt < Tin){
        const float* base = xin + ((size_t)(b*RES_C + c))*T_IN + gtt;
        v0 = base[0]; v1 = base[T_IN];
      }
      unsigned u = (unsigned)f2bf(v0) | ((unsigned)f2bf(v1) << 16);
      int slot = k0 >> 3;
      *(unsigned*)(Bx + t*512 + ((slot ^ (t & 31)) << 4) + ((2*k0) & 15)) = u;
    }
  }
  __syncthreads();

  // ---- dilated GEMM: M=256 (f/g interleaved), K=256, N=64. wave owns 32 rows.
  f32x4 acc[2][4] = {};
  {
    const unsigned short* A = dilWb + (size_t)layer*256*256 + (size_t)(wave*32)*256;
    for (int kk = 0; kk < 8; ++kk){
      int k0 = kk*32 + q*8;
      bf16x8 a0 = *(const bf16x8*)(A + (size_t)r16*256 + k0);
      bf16x8 a1 = *(const bf16x8*)(A + (size_t)(16 + r16)*256 + k0);
      int slot = k0 >> 3;
      #pragma unroll
      for (int nt = 0; nt < 4; ++nt){
        int t = nt*16 + r16;
        bf16x8 bf = *(const bf16x8*)(Bx + t*512 + ((slot ^ (t & 31)) << 4));
        acc[0][nt] = __builtin_amdgcn_mfma_f32_16x16x32_bf16(a0, bf, acc[0][nt], 0, 0, 0);
        acc[1][nt] = __builtin_amdgcn_mfma_f32_16x16x32_bf16(a1, bf, acc[1][nt], 0, 0, 0);
      }
    }
  }

  // ---- gate + write z to Bz (rows 4q+r hold f,g,f,g of channels 2q,2q+1)
  {
    const float* cb = cbias + ((size_t)layer*NB + b)*256 + wave*32;
    #pragma unroll
    for (int mt = 0; mt < 2; ++mt){
      float bf0 = cb[mt*16 + 4*q + 0];
      float bg0 = cb[mt*16 + 4*q + 1];
      float bf1 = cb[mt*16 + 4*q + 2];
      float bg1 = cb[mt*16 + 4*q + 3];
      int ch0 = wave*16 + mt*8 + 2*q;
      int slot = ch0 >> 3;
      #pragma unroll
      for (int nt = 0; nt < 4; ++nt){
        float z0 = ftanh(acc[mt][nt][0] + bf0) * fsigmoid(acc[mt][nt][1] + bg0);
        float z1 = ftanh(acc[mt][nt][2] + bf1) * fsigmoid(acc[mt][nt][3] + bg1);
        int t = nt*16 + r16;
        unsigned u = (unsigned)f2bf(z0) | ((unsigned)f2bf(z1) << 16);
        *(unsigned*)(Bz + t*256 + ((slot ^ (t & 15)) << 4) + ((2*ch0) & 15)) = u;
      }
    }
  }
  __syncthreads();

  // ---- skip GEMM: M=256, K=128. wave owns 32 rows.
  {
    f32x4 sacc[2][4] = {};
    const unsigned short* A = skipWb + (size_t)layer*256*128 + (size_t)(wave*32)*128;
    for (int kk = 0; kk < 4; ++kk){
      int k0 = kk*32 + q*8;
      bf16x8 a0 = *(const bf16x8*)(A + (size_t)r16*128 + k0);
      bf16x8 a1 = *(const bf16x8*)(A + (size_t)(16 + r16)*128 + k0);
      int slot = k0 >> 3;
      #pragma unroll
      for (int nt = 0; nt < 4; ++nt){
        int t = nt*16 + r16;
        bf16x8 bf = *(const bf16x8*)(Bz + t*256 + ((slot ^ (t & 15)) << 4));
        sacc[0][nt] = __builtin_amdgcn_mfma_f32_16x16x32_bf16(a0, bf, sacc[0][nt], 0, 0, 0);
        sacc[1][nt] = __builtin_amdgcn_mfma_f32_16x16x32_bf16(a1, bf, sacc[1][nt], 0, 0, 0);
      }
    }
    const float* sb = skip_b + layer*256 + wave*32;
    const int woff = Tout - T_FIN;
    #pragma unroll
    for (int mt = 0; mt < 2; ++mt){
      #pragma unroll
      for (int nt = 0; nt < 4; ++nt){
        int gt = t0 + nt*16 + r16;
        int tw = gt - woff;
        if (gt < Tout && tw >= 0){
          #pragma unroll
          for (int rr = 0; rr < 4; ++rr){
            int m = wave*32 + mt*16 + 4*q + rr;
            size_t si = ((size_t)(b*SKIPC + m))*T_FIN + tw;
            float v = sacc[mt][nt][rr] + sb[mt*16 + 4*q + rr];
            skip[si] = first ? v : (skip[si] + v);
          }
        }
      }
    }
  }

  // ---- res GEMM: M=128, K=128. wave owns 16 rows. (skipped on last layer)
  if (!last){
    f32x4 racc[4] = {};
    const unsigned short* A = resWb + (size_t)layer*128*128 + (size_t)(wave*16)*128;
    for (int kk = 0; kk < 4; ++kk){
      int k0 = kk*32 + q*8;
      bf16x8 a0 = *(const bf16x8*)(A + (size_t)r16*128 + k0);
      int slot = k0 >> 3;
      #pragma unroll
      for (int nt = 0; nt < 4; ++nt){
        int t = nt*16 + r16;
        bf16x8 bf = *(const bf16x8*)(Bz + t*256 + ((slot ^ (t & 15)) << 4));
        racc[nt] = __builtin_amdgcn_mfma_f32_16x16x32_bf16(a0, bf, racc[nt], 0, 0, 0);
      }
    }
    const float* rb = res_b + layer*128 + wave*16;
    #pragma unroll
    for (int nt = 0; nt < 4; ++nt){
      int gt = t0 + nt*16 + r16;
      if (gt < Tout){
        #pragma unroll
        for (int rr = 0; rr < 4; ++rr){
          int m = wave*16 + 4*q + rr;
          size_t base = ((size_t)(b*RES_C + m))*T_IN;
          xout[base + gt] = racc[nt][rr] + rb[4*q + rr] + xin[base + gt + d];
        }
      }
    }
  }
}

// ---------------------------------------------------------------------------
// final: out = sigmoid(end_b + endW @ tanh(skip + cend)) via MFMA, M=240(pad 256), K=256
__global__ __launch_bounds__(BLK) void final_mfma(const float* __restrict__ skip,
    const float* __restrict__ cend, const unsigned short* __restrict__ endWb,
    const float* __restrict__ end_b, float* __restrict__ out){
  __shared__ char Bs[64*512];   // [t][s:256] bf16, slot ^= (t&31)
  const int tid = threadIdx.x;
  const int b = blockIdx.y; const int t0 = blockIdx.x*TILE;
  const int lane = tid & 63;
  const int wave = __builtin_amdgcn_readfirstlane(tid >> 6);
  const int q = lane >> 4;
  const int r16 = lane & 15;

  {
    const int t = lane;
    const int gt = t0 + t;
    #pragma unroll
    for (int i = 0; i < 32; i += 2){
      int s0 = wave*32 + i;
      float v0 = 0.f, v1 = 0.f;
      if (gt < T_FIN){
        const float* base = skip + ((size_t)(b*SKIPC + s0))*T_FIN + gt;
        v0 = ftanh(base[0]     + cend[b*256 + s0]);
        v1 = ftanh(base[T_FIN] + cend[b*256 + s0 + 1]);
      }
      unsigned u = (unsigned)f2bf(v0) | ((unsigned)f2bf(v1) << 16);
      int slot = s0 >> 3;
      *(unsigned*)(Bs + t*512 + ((slot ^ (t & 31)) << 4) + ((2*s0) & 15)) = u;
    }
  }
  __syncthreads();

  f32x4 acc[2][4] = {};
  const unsigned short* A = endWb + (size_t)(wave*32)*256;
  for (int kk = 0; kk < 8; ++kk){
    int k0 = kk*32 + q*8;
    bf16x8 a0 = *(const bf16x8*)(A + (size_t)r16*256 + k0);
    bf16x8 a1 = *(const bf16x8*)(A + (size_t)(16 + r16)*256 + k0);
    int slot = k0 >> 3;
    #pragma unroll
    for (int nt = 0; nt < 4; ++nt){
      int t = nt*16 + r16;
      bf16x8 bf = *(const bf16x8*)(Bs + t*512 + ((slot ^ (t & 31)) << 4));
      acc[0][nt] = __builtin_amdgcn_mfma_f32_16x16x32_bf16(a0, bf, acc[0][nt], 0, 0, 0);
      acc[1][nt] = __builtin_amdgcn_mfma_f32_16x16x32_bf16(a1, bf, acc[1][nt], 0, 0, 0);
    }
  }
  #pragma unroll
  for (int mt = 0; mt < 2; ++mt){
    #pragma unroll
    for (int nt = 0; nt < 4; ++nt){
      int gt = t0 + nt*16 + r16;
      if (gt < T_FIN){
        #pragma unroll
        for (int rr = 0; rr < 4; ++rr){
          int m = wave*32 + mt*16 + 4*q + rr;
          if (m < OUTC)
            out[((size_t)(b*OUTC + m))*T_FIN + gt] = fsigmoid(acc[mt][nt][rr] + end_b[m]);
        }
      }
    }
  }
}

// ---------------------------------------------------------------------------
extern "C" void kernel_launch(void* const* d_in, const int* in_sizes, int n_in,
                              void* d_out, int out_size, void* d_ws, size_t ws_size,
                              hipStream_t stream){
  const float* input     = (const float*)d_in[0];
  const float* condition = (const float*)d_in[1];
  const float* start_w   = (const float*)d_in[2];
  const float* start_b   = (const float*)d_in[3];
  const float* dil_w     = (const float*)d_in[4];
  const float* dil_b     = (const float*)d_in[5];
  const float* cond_w    = (const float*)d_in[6];
  const float* cond_b    = (const float*)d_in[7];
  const float* res_w     = (const float*)d_in[8];
  const float* res_b     = (const float*)d_in[9];
  const float* skip_w    = (const float*)d_in[10];
  const float* skip_b    = (const float*)d_in[11];
  const float* end_w     = (const float*)d_in[12];
  const float* end_b     = (const float*)d_in[13];
  const float* cend_w    = (const float*)d_in[14];
  const float* cend_b    = (const float*)d_in[15];
  float* out = (float*)d_out;

  char* ws = (char*)d_ws;
  size_t off = 0;
  auto carve = [&](size_t bytes) -> char* {
    char* p = ws + off; off = (off + bytes + 255) & ~(size_t)255; return p;
  };
  float* xA   = (float*)carve((size_t)NB*RES_C*T_IN*4);
  float* xB   = (float*)carve((size_t)NB*RES_C*T_IN*4);
  float* skip = (float*)carve((size_t)NB*SKIPC*T_FIN*4);
  unsigned short* dilWb  = (unsigned short*)carve((size_t)NDIL*2);
  unsigned short* skipWb = (unsigned short*)carve((size_t)NSKP*2);
  unsigned short* resWb  = (unsigned short*)carve((size_t)NRES*2);
  unsigned short* endWb  = (unsigned short*)carve((size_t)NEND*2);
  float* cbias = (float*)carve((size_t)NLAYERS*NB*256*4);
  float* cend  = (float*)carve((size_t)NB*256*4);

  prep_weights<<<2048, 256, 0, stream>>>(dil_w, skip_w, res_w, end_w, dilWb, skipWb, resWb, endWb);
  prep_bias<<<NLAYERS*NB + NB, 256, 0, stream>>>(condition, dil_b, cond_w, cond_b, cend_w, cend_b, cbias, cend);

  {
    dim3 grid((T0LEN + TILE - 1)/TILE, NB);
    start_kernel<<<grid, BLK, 0, stream>>>(input, start_w, start_b, xA);
  }

  int dils[NLAYERS]; int n = 0;
  for (int bb = 0; bb < 2; ++bb){ int nn = (bb==0) ? 10 : 9; for (int k = 0; k < nn; ++k) dils[n++] = 1<<k; }

  float* xin = xA; float* xo = xB;
  int Tin = T0LEN;
  for (int i = 0; i < NLAYERS; ++i){
    int d = dils[i]; int Tout = Tin - d;
    dim3 grid((Tout + TILE - 1)/TILE, NB);
    layer_mfma<<<grid, BLK, 0, stream>>>(xin, xo, skip, dilWb, skipWb, resWb, cbias,
                                         skip_b, res_b, i, d, Tin, Tout,
                                         (i==0)?1:0, (i==NLAYERS-1)?1:0);
    float* tmp = xin; xin = xo; xo = tmp;
    Tin = Tout;
  }

  {
    dim3 grid((T_FIN + TILE - 1)/TILE, NB);
    final_mfma<<<grid, BLK, 0, stream>>>(skip, cend, endWb, end_b, out);
  }
}

// Round 5
// 834.206 us; speedup vs baseline: 4.8839x; 1.1419x over previous
//
#include <hip/hip_runtime.h>
#include <cstdint>
#include <cstddef>

#define NLAYERS 19
#define NB 4
#define RES_C 128
#define DIL2 256
#define SKIPC 256
#define INC 60
#define CONDC 80
#define OUTC 240
#define T_IN 6144
#define T0LEN 6135   // after start conv (K=10, VALID)
#define T_FIN 4601
#define TILE 64
#define BLK 512

#define NDIL (NLAYERS*256*256)
#define NSKP (NLAYERS*256*128)
#define NRES (NLAYERS*128*128)
#define NEND (256*256)
#define NSTART (10*128*64)

typedef short bf16x8 __attribute__((ext_vector_type(8)));
typedef float f32x4 __attribute__((ext_vector_type(4)));
typedef unsigned uint32x2 __attribute__((ext_vector_type(2)));

#if __has_builtin(__builtin_amdgcn_exp2f)
#define EXP2F(x) __builtin_amdgcn_exp2f(x)
#else
#define EXP2F(x) exp2f(x)
#endif
#if __has_builtin(__builtin_amdgcn_rcpf)
#define RCPF(x) __builtin_amdgcn_rcpf(x)
#else
#define RCPF(x) (1.0f/(x))
#endif

__device__ __forceinline__ float fexp(float x){ return EXP2F(x * 1.4426950408889634f); }
__device__ __forceinline__ float fsigmoid(float x){ return RCPF(1.0f + fexp(-x)); }
__device__ __forceinline__ float ftanh(float x){ return 1.0f - 2.0f * RCPF(1.0f + fexp(2.0f*x)); }

__device__ __forceinline__ unsigned short f2bf(float f){
  unsigned u = __builtin_bit_cast(unsigned, f);
  u = u + 0x7FFFu + ((u >> 16) & 1u);   // RNE (finite values only)
  return (unsigned short)(u >> 16);
}

// ---------------------------------------------------------------------------
// Pack weights to bf16. dilWb rows interleaved: m even=filter ch m/2, m odd=gate ch m/2.
// K order: k<128 -> tap0 (x[t]) channel k ; k>=128 -> tap1 (x[t+d]) channel k-128.
// startWb: [tap k][oc:128][c:64 (60 used)]
__global__ void prep_weights(const float* __restrict__ dil_w, const float* __restrict__ skip_w,
                             const float* __restrict__ res_w, const float* __restrict__ end_w,
                             const float* __restrict__ start_w,
                             unsigned short* __restrict__ dilWb, unsigned short* __restrict__ skipWb,
                             unsigned short* __restrict__ resWb, unsigned short* __restrict__ endWb,
                             unsigned short* __restrict__ startWb){
  const int total = NDIL + NSKP + NRES + NEND + NSTART;
  for (int idx = blockIdx.x*256 + threadIdx.x; idx < total; idx += gridDim.x*256){
    if (idx < NDIL){
      int l = idx >> 16; int rem = idx & 65535; int m = rem >> 8; int k = rem & 255;
      int o = ((m & 1) << 7) + (m >> 1); int c = k & 127; int tap = k >> 7;
      dilWb[idx] = f2bf(dil_w[(((size_t)l*256 + o)*128 + c)*2 + tap]);
    } else if (idx < NDIL + NSKP){
      int j = idx - NDIL;
      skipWb[j] = f2bf(skip_w[j]);           // [l][m][k] identical layout
    } else if (idx < NDIL + NSKP + NRES){
      int j = idx - NDIL - NSKP;
      resWb[j] = f2bf(res_w[j]);             // [l][m][k] identical layout
    } else if (idx < NDIL + NSKP + NRES + NEND){
      int j = idx - NDIL - NSKP - NRES;
      int m = j >> 8; int k = j & 255;
      endWb[j] = (m < OUTC) ? f2bf(end_w[(size_t)m*256 + k]) : 0;
    } else {
      int j = idx - NDIL - NSKP - NRES - NEND;
      int k = j >> 13; int rem = j & 8191; int oc = rem >> 6; int c = rem & 63;
      startWb[j] = (c < INC) ? f2bf(start_w[((size_t)oc*INC + c)*10 + k]) : 0;
    }
  }
}

// ---------------------------------------------------------------------------
// cbias[l][b][m] = dil_b[o(m)] + cond_b[l][o(m)] + sum_c cond_w[l][o(m)][c]*cond[b][c]
// cend[b][o]    = cend_b[o]    + sum_c cend_w[o][c]   * cond[b][c]
__global__ void prep_bias(const float* __restrict__ cond, const float* __restrict__ dil_b,
                          const float* __restrict__ cond_w, const float* __restrict__ cond_b,
                          const float* __restrict__ cend_w, const float* __restrict__ cend_b,
                          float* __restrict__ cbias, float* __restrict__ cend){
  int blk = blockIdx.x; int m = threadIdx.x;
  if (blk < NLAYERS*NB){
    int l = blk >> 2, b = blk & 3;
    int o = ((m & 1) << 7) + (m >> 1);
    float acc = dil_b[l*256 + o] + cond_b[l*256 + o];
    const float* w = cond_w + ((size_t)l*256 + o)*CONDC;
    const float* cv = cond + b*CONDC;
    for (int c = 0; c < CONDC; ++c) acc += w[c]*cv[c];
    cbias[((size_t)l*NB + b)*256 + m] = acc;
  } else {
    int b = blk - NLAYERS*NB;
    float acc = cend_b[m];
    const float* w = cend_w + (size_t)m*CONDC;
    const float* cv = cond + b*CONDC;
    for (int c = 0; c < CONDC; ++c) acc += w[c]*cv[c];
    cend[b*256 + m] = acc;
  }
}

// ---------------------------------------------------------------------------
// start conv via MFMA, tap-decomposed: out[oc][t] = b[oc] + sum_k Wk @ in[:, t+k]
__global__ __launch_bounds__(BLK) void start_mfma(const float* __restrict__ in,
    const unsigned short* __restrict__ startWb, const float* __restrict__ bias,
    float* __restrict__ xout){
  __shared__ char Bs[80*128];   // [tt:80][c:64] bf16, 16B slots: slot ^= (tt&7)
  const int tid = threadIdx.x;
  const int b = blockIdx.y; const int t0 = blockIdx.x*TILE;
  const int lane = tid & 63;
  const int wave = __builtin_amdgcn_readfirstlane(tid >> 6);
  const int q = lane >> 4, r16 = lane & 15;

  #pragma unroll
  for (int i = 0; i < 5; ++i){
    int j = tid + i*BLK;              // 0..2559 = 32 c-pairs x 80 tt
    int c2 = j / 80, tt = j % 80;
    int c = 2*c2; int gt = t0 + tt;
    float v0 = 0.f, v1 = 0.f;
    if (gt < T_IN && c < INC){
      const float* base = in + ((size_t)(b*INC + c))*T_IN + gt;
      v0 = base[0]; v1 = base[T_IN];
    }
    unsigned u = (unsigned)f2bf(v0) | ((unsigned)f2bf(v1) << 16);
    int slot = c2 >> 2;
    *(unsigned*)(Bs + tt*128 + ((((slot ^ (tt & 7)) << 4)) | ((4*c2) & 15))) = u;
  }
  __syncthreads();

  f32x4 acc[4] = {};
  for (int k = 0; k < 10; ++k){
    const unsigned short* A = startWb + ((size_t)k*128 + wave*16)*64;
    #pragma unroll
    for (int kk = 0; kk < 2; ++kk){
      int k0 = kk*32 + q*8;
      bf16x8 a = *(const bf16x8*)(A + (size_t)r16*64 + k0);
      int slot = k0 >> 3;
      #pragma unroll
      for (int nt = 0; nt < 4; ++nt){
        int t = nt*16 + r16 + k;
        bf16x8 bf = *(const bf16x8*)(Bs + t*128 + ((slot ^ (t & 7)) << 4));
        acc[nt] = __builtin_amdgcn_mfma_f32_16x16x32_bf16(a, bf, acc[nt], 0, 0, 0);
      }
    }
  }
  const float* bb = bias + wave*16;
  #pragma unroll
  for (int nt = 0; nt < 4; ++nt){
    int gt = t0 + nt*16 + r16;
    if (gt < T0LEN){
      #pragma unroll
      for (int rr = 0; rr < 4; ++rr){
        int oc = wave*16 + 4*q + rr;
        xout[(size_t)(b*RES_C + oc)*T_IN + gt] = acc[nt][rr] + bb[4*q + rr];
      }
    }
  }
}

// ---------------------------------------------------------------------------
// Fused MFMA layer (R2-proven). x fp32 in global; B operands bf16 in swizzled LDS.
__global__ __launch_bounds__(BLK) void layer_mfma(
    const float* __restrict__ xin, float* __restrict__ xout, float* __restrict__ skip,
    const unsigned short* __restrict__ dilWb, const unsigned short* __restrict__ skipWb,
    const unsigned short* __restrict__ resWb, const float* __restrict__ cbias,
    const float* __restrict__ skip_b, const float* __restrict__ res_b,
    int layer, int d, int Tin, int Tout, int first, int last){
  __shared__ char Bx[64*512];   // [t][k:256] bf16, 16B slots swizzled: slot^= (t&31)
  __shared__ char Bz[64*256];   // [t][ch:128] bf16, slot ^= (t&15)
  const int tid = threadIdx.x;
  const int b = blockIdx.y; const int t0 = blockIdx.x*TILE;
  const int lane = tid & 63;
  const int wave = __builtin_amdgcn_readfirstlane(tid >> 6);
  const int q = lane >> 4;          // 0..3
  const int r16 = lane & 15;        // row-in-Afrag / col-in-Bfrag

  // ---- stage Bx: k<128 = x[t] ch k ; k>=128 = x[t+d] ch k-128
  {
    const int t = lane;
    const int gt = t0 + t;
    #pragma unroll
    for (int i = 0; i < 32; i += 2){
      int k0 = wave*32 + i;
      int tap = k0 >> 7; int c = k0 & 127;
      int gtt = gt + (tap ? d : 0);
      float v0 = 0.f, v1 = 0.f;
      if (gtt < Tin){
        const float* base = xin + ((size_t)(b*RES_C + c))*T_IN + gtt;
        v0 = base[0]; v1 = base[T_IN];
      }
      unsigned u = (unsigned)f2bf(v0) | ((unsigned)f2bf(v1) << 16);
      int slot = k0 >> 3;
      *(unsigned*)(Bx + t*512 + ((slot ^ (t & 31)) << 4) + ((2*k0) & 15)) = u;
    }
  }
  __syncthreads();

  // ---- dilated GEMM: M=256 (f/g interleaved), K=256, N=64. wave owns 32 rows.
  f32x4 acc[2][4] = {};
  {
    const unsigned short* A = dilWb + (size_t)layer*256*256 + (size_t)(wave*32)*256;
    for (int kk = 0; kk < 8; ++kk){
      int k0 = kk*32 + q*8;
      bf16x8 a0 = *(const bf16x8*)(A + (size_t)r16*256 + k0);
      bf16x8 a1 = *(const bf16x8*)(A + (size_t)(16 + r16)*256 + k0);
      int slot = k0 >> 3;
      #pragma unroll
      for (int nt = 0; nt < 4; ++nt){
        int t = nt*16 + r16;
        bf16x8 bf = *(const bf16x8*)(Bx + t*512 + ((slot ^ (t & 31)) << 4));
        acc[0][nt] = __builtin_amdgcn_mfma_f32_16x16x32_bf16(a0, bf, acc[0][nt], 0, 0, 0);
        acc[1][nt] = __builtin_amdgcn_mfma_f32_16x16x32_bf16(a1, bf, acc[1][nt], 0, 0, 0);
      }
    }
  }

  // ---- gate + write z to Bz (rows 4q+r hold f,g,f,g of channels 2q,2q+1)
  {
    const float* cb = cbias + ((size_t)layer*NB + b)*256 + wave*32;
    #pragma unroll
    for (int mt = 0; mt < 2; ++mt){
      float bf0 = cb[mt*16 + 4*q + 0];
      float bg0 = cb[mt*16 + 4*q + 1];
      float bf1 = cb[mt*16 + 4*q + 2];
      float bg1 = cb[mt*16 + 4*q + 3];
      int ch0 = wave*16 + mt*8 + 2*q;
      int slot = ch0 >> 3;
      #pragma unroll
      for (int nt = 0; nt < 4; ++nt){
        float z0 = ftanh(acc[mt][nt][0] + bf0) * fsigmoid(acc[mt][nt][1] + bg0);
        float z1 = ftanh(acc[mt][nt][2] + bf1) * fsigmoid(acc[mt][nt][3] + bg1);
        int t = nt*16 + r16;
        unsigned u = (unsigned)f2bf(z0) | ((unsigned)f2bf(z1) << 16);
        *(unsigned*)(Bz + t*256 + ((slot ^ (t & 15)) << 4) + ((2*ch0) & 15)) = u;
      }
    }
  }
  __syncthreads();

  // ---- skip GEMM: M=256, K=128. wave owns 32 rows.
  {
    f32x4 sacc[2][4] = {};
    const unsigned short* A = skipWb + (size_t)layer*256*128 + (size_t)(wave*32)*128;
    for (int kk = 0; kk < 4; ++kk){
      int k0 = kk*32 + q*8;
      bf16x8 a0 = *(const bf16x8*)(A + (size_t)r16*128 + k0);
      bf16x8 a1 = *(const bf16x8*)(A + (size_t)(16 + r16)*128 + k0);
      int slot = k0 >> 3;
      #pragma unroll
      for (int nt = 0; nt < 4; ++nt){
        int t = nt*16 + r16;
        bf16x8 bf = *(const bf16x8*)(Bz + t*256 + ((slot ^ (t & 15)) << 4));
        sacc[0][nt] = __builtin_amdgcn_mfma_f32_16x16x32_bf16(a0, bf, sacc[0][nt], 0, 0, 0);
        sacc[1][nt] = __builtin_amdgcn_mfma_f32_16x16x32_bf16(a1, bf, sacc[1][nt], 0, 0, 0);
      }
    }
    const float* sb = skip_b + layer*256 + wave*32;
    const int woff = Tout - T_FIN;
    #pragma unroll
    for (int mt = 0; mt < 2; ++mt){
      #pragma unroll
      for (int nt = 0; nt < 4; ++nt){
        int gt = t0 + nt*16 + r16;
        int tw = gt - woff;
        if (gt < Tout && tw >= 0){
          #pragma unroll
          for (int rr = 0; rr < 4; ++rr){
            int m = wave*32 + mt*16 + 4*q + rr;
            size_t si = ((size_t)(b*SKIPC + m))*T_FIN + tw;
            float v = sacc[mt][nt][rr] + sb[mt*16 + 4*q + rr];
            skip[si] = first ? v : (skip[si] + v);
          }
        }
      }
    }
  }

  // ---- res GEMM: M=128, K=128. wave owns 16 rows. (skipped on last layer)
  if (!last){
    f32x4 racc[4] = {};
    const unsigned short* A = resWb + (size_t)layer*128*128 + (size_t)(wave*16)*128;
    for (int kk = 0; kk < 4; ++kk){
      int k0 = kk*32 + q*8;
      bf16x8 a0 = *(const bf16x8*)(A + (size_t)r16*128 + k0);
      int slot = k0 >> 3;
      #pragma unroll
      for (int nt = 0; nt < 4; ++nt){
        int t = nt*16 + r16;
        bf16x8 bf = *(const bf16x8*)(Bz + t*256 + ((slot ^ (t & 15)) << 4));
        racc[nt] = __builtin_amdgcn_mfma_f32_16x16x32_bf16(a0, bf, racc[nt], 0, 0, 0);
      }
    }
    const float* rb = res_b + layer*RES_C + wave*16;
    #pragma unroll
    for (int nt = 0; nt < 4; ++nt){
      int gt = t0 + nt*16 + r16;
      if (gt < Tout){
        #pragma unroll
        for (int rr = 0; rr < 4; ++rr){
          int m = wave*16 + 4*q + rr;
          size_t base = ((size_t)(b*RES_C + m))*T_IN;
          xout[base + gt] = racc[nt][rr] + rb[4*q + rr] + xin[base + gt + d];
        }
      }
    }
  }
}

// ---------------------------------------------------------------------------
// final (R2-proven): out = sigmoid(end_b + endW @ tanh(skip + cend)), M=240(pad 256), K=256
__global__ __launch_bounds__(BLK) void final_mfma(const float* __restrict__ skip,
    const float* __restrict__ cend, const unsigned short* __restrict__ endWb,
    const float* __restrict__ end_b, float* __restrict__ out){
  __shared__ char Bs[64*512];   // [t][s:256] bf16, slot ^= (t&31)
  const int tid = threadIdx.x;
  const int b = blockIdx.y; const int t0 = blockIdx.x*TILE;
  const int lane = tid & 63;
  const int wave = __builtin_amdgcn_readfirstlane(tid >> 6);
  const int q = lane >> 4;
  const int r16 = lane & 15;

  {
    const int t = lane;
    const int gt = t0 + t;
    #pragma unroll
    for (int i = 0; i < 32; i += 2){
      int s0 = wave*32 + i;
      float v0 = 0.f, v1 = 0.f;
      if (gt < T_FIN){
        const float* base = skip + ((size_t)(b*SKIPC + s0))*T_FIN + gt;
        v0 = ftanh(base[0]     + cend[b*256 + s0]);
        v1 = ftanh(base[T_FIN] + cend[b*256 + s0 + 1]);
      }
      unsigned u = (unsigned)f2bf(v0) | ((unsigned)f2bf(v1) << 16);
      int slot = s0 >> 3;
      *(unsigned*)(Bs + t*512 + ((slot ^ (t & 31)) << 4) + ((2*s0) & 15)) = u;
    }
  }
  __syncthreads();

  f32x4 acc[2][4] = {};
  const unsigned short* A = endWb + (size_t)(wave*32)*256;
  for (int kk = 0; kk < 8; ++kk){
    int k0 = kk*32 + q*8;
    bf16x8 a0 = *(const bf16x8*)(A + (size_t)r16*256 + k0);
    bf16x8 a1 = *(const bf16x8*)(A + (size_t)(16 + r16)*256 + k0);
    int slot = k0 >> 3;
    #pragma unroll
    for (int nt = 0; nt < 4; ++nt){
      int t = nt*16 + r16;
      bf16x8 bf = *(const bf16x8*)(Bs + t*512 + ((slot ^ (t & 31)) << 4));
      acc[0][nt] = __builtin_amdgcn_mfma_f32_16x16x32_bf16(a0, bf, acc[0][nt], 0, 0, 0);
      acc[1][nt] = __builtin_amdgcn_mfma_f32_16x16x32_bf16(a1, bf, acc[1][nt], 0, 0, 0);
    }
  }
  #pragma unroll
  for (int mt = 0; mt < 2; ++mt){
    #pragma unroll
    for (int nt = 0; nt < 4; ++nt){
      int gt = t0 + nt*16 + r16;
      if (gt < T_FIN){
        #pragma unroll
        for (int rr = 0; rr < 4; ++rr){
          int m = wave*32 + mt*16 + 4*q + rr;
          if (m < OUTC)
            out[((size_t)(b*OUTC + m))*T_FIN + gt] = fsigmoid(acc[mt][nt][rr] + end_b[m]);
        }
      }
    }
  }
}

// ---------------------------------------------------------------------------
extern "C" void kernel_launch(void* const* d_in, const int* in_sizes, int n_in,
                              void* d_out, int out_size, void* d_ws, size_t ws_size,
                              hipStream_t stream){
  const float* input     = (const float*)d_in[0];
  const float* condition = (const float*)d_in[1];
  const float* start_w   = (const float*)d_in[2];
  const float* start_b   = (const float*)d_in[3];
  const float* dil_w     = (const float*)d_in[4];
  const float* dil_b     = (const float*)d_in[5];
  const float* cond_w    = (const float*)d_in[6];
  const float* cond_b    = (const float*)d_in[7];
  const float* res_w     = (const float*)d_in[8];
  const float* res_b     = (const float*)d_in[9];
  const float* skip_w    = (const float*)d_in[10];
  const float* skip_b    = (const float*)d_in[11];
  const float* end_w     = (const float*)d_in[12];
  const float* end_b     = (const float*)d_in[13];
  const float* cend_w    = (const float*)d_in[14];
  const float* cend_b    = (const float*)d_in[15];
  float* out = (float*)d_out;

  // Footprint: 46.49 MiB (R2's proven 46.33 MiB + 0.16 MiB startWb).
  // R3 (69.3 MiB) and R4 (49.9 MiB) both failed with structured-wrong output;
  // ws overflow past ~48 MiB is the prime suspect. Stay at R2's budget.
  char* ws = (char*)d_ws;
  size_t off = 0;
  auto carve = [&](size_t bytes) -> char* {
    char* p = ws + off; off = (off + bytes + 255) & ~(size_t)255; return p;
  };
  float* xA   = (float*)carve((size_t)NB*RES_C*T_IN*4);
  float* xB   = (float*)carve((size_t)NB*RES_C*T_IN*4);
  float* skip = (float*)carve((size_t)NB*SKIPC*T_FIN*4);
  unsigned short* dilWb   = (unsigned short*)carve((size_t)NDIL*2);
  unsigned short* skipWb  = (unsigned short*)carve((size_t)NSKP*2);
  unsigned short* resWb   = (unsigned short*)carve((size_t)NRES*2);
  unsigned short* endWb   = (unsigned short*)carve((size_t)NEND*2);
  unsigned short* startWb = (unsigned short*)carve((size_t)NSTART*2);
  float* cbias = (float*)carve((size_t)NLAYERS*NB*256*4);
  float* cend  = (float*)carve((size_t)NB*256*4);

  prep_weights<<<2048, 256, 0, stream>>>(dil_w, skip_w, res_w, end_w, start_w,
                                         dilWb, skipWb, resWb, endWb, startWb);
  prep_bias<<<NLAYERS*NB + NB, 256, 0, stream>>>(condition, dil_b, cond_w, cond_b,
                                                 cend_w, cend_b, cbias, cend);

  {
    dim3 grid((T0LEN + TILE - 1)/TILE, NB);
    start_mfma<<<grid, BLK, 0, stream>>>(input, startWb, start_b, xA);
  }

  int dils[NLAYERS]; int n = 0;
  for (int bb = 0; bb < 2; ++bb){ int nn = (bb==0) ? 10 : 9; for (int k = 0; k < nn; ++k) dils[n++] = 1<<k; }

  float* xin = xA; float* xo = xB;
  int Tin = T0LEN;
  for (int i = 0; i < NLAYERS; ++i){
    int d = dils[i]; int Tout = Tin - d;
    dim3 grid((Tout + TILE - 1)/TILE, NB);
    layer_mfma<<<grid, BLK, 0, stream>>>(xin, xo, skip, dilWb, skipWb, resWb, cbias,
                                         skip_b, res_b, i, d, Tin, Tout,
                                         (i==0)?1:0, (i==NLAYERS-1)?1:0);
    float* tmp = xin; xin = xo; xo = tmp;
    Tin = Tout;
  }

  {
    dim3 grid((T_FIN + TILE - 1)/TILE, NB);
    final_mfma<<<grid, BLK, 0, stream>>>(skip, cend, endWb, end_b, out);
  }
}

// Round 6
// 775.607 us; speedup vs baseline: 5.2529x; 1.0756x over previous
//
#include <hip/hip_runtime.h>
#include <cstdint>
#include <cstddef>

#define NLAYERS 19
#define NB 4
#define RES_C 128
#define DIL2 256
#define SKIPC 256
#define INC 60
#define CONDC 80
#define OUTC 240
#define T_IN 6144
#define T0LEN 6135   // after start conv (K=10, VALID)
#define T_FIN 4601
#define TILE 64      // start/final tile
#define LTILE 32     // layer tile (R6: halved -> 768 blocks, 3/CU)
#define BLK 512

#define NDIL (NLAYERS*256*256)
#define NSKP (NLAYERS*256*128)
#define NRES (NLAYERS*128*128)
#define NEND (256*256)
#define NSTART (10*128*64)

typedef short bf16x8 __attribute__((ext_vector_type(8)));
typedef float f32x4 __attribute__((ext_vector_type(4)));
typedef unsigned uint32x2 __attribute__((ext_vector_type(2)));

#if __has_builtin(__builtin_amdgcn_exp2f)
#define EXP2F(x) __builtin_amdgcn_exp2f(x)
#else
#define EXP2F(x) exp2f(x)
#endif
#if __has_builtin(__builtin_amdgcn_rcpf)
#define RCPF(x) __builtin_amdgcn_rcpf(x)
#else
#define RCPF(x) (1.0f/(x))
#endif

__device__ __forceinline__ float fexp(float x){ return EXP2F(x * 1.4426950408889634f); }
__device__ __forceinline__ float fsigmoid(float x){ return RCPF(1.0f + fexp(-x)); }
__device__ __forceinline__ float ftanh(float x){ return 1.0f - 2.0f * RCPF(1.0f + fexp(2.0f*x)); }

__device__ __forceinline__ unsigned short f2bf(float f){
  unsigned u = __builtin_bit_cast(unsigned, f);
  u = u + 0x7FFFu + ((u >> 16) & 1u);   // RNE (finite values only)
  return (unsigned short)(u >> 16);
}

// ---------------------------------------------------------------------------
// Pack weights to bf16. dilWb rows interleaved: m even=filter ch m/2, m odd=gate ch m/2.
// K order: k<128 -> tap0 (x[t]) channel k ; k>=128 -> tap1 (x[t+d]) channel k-128.
// startWb: [tap k][oc:128][c:64 (60 used)]
__global__ void prep_weights(const float* __restrict__ dil_w, const float* __restrict__ skip_w,
                             const float* __restrict__ res_w, const float* __restrict__ end_w,
                             const float* __restrict__ start_w,
                             unsigned short* __restrict__ dilWb, unsigned short* __restrict__ skipWb,
                             unsigned short* __restrict__ resWb, unsigned short* __restrict__ endWb,
                             unsigned short* __restrict__ startWb){
  const int total = NDIL + NSKP + NRES + NEND + NSTART;
  for (int idx = blockIdx.x*256 + threadIdx.x; idx < total; idx += gridDim.x*256){
    if (idx < NDIL){
      int l = idx >> 16; int rem = idx & 65535; int m = rem >> 8; int k = rem & 255;
      int o = ((m & 1) << 7) + (m >> 1); int c = k & 127; int tap = k >> 7;
      dilWb[idx] = f2bf(dil_w[(((size_t)l*256 + o)*128 + c)*2 + tap]);
    } else if (idx < NDIL + NSKP){
      int j = idx - NDIL;
      skipWb[j] = f2bf(skip_w[j]);           // [l][m][k] identical layout
    } else if (idx < NDIL + NSKP + NRES){
      int j = idx - NDIL - NSKP;
      resWb[j] = f2bf(res_w[j]);             // [l][m][k] identical layout
    } else if (idx < NDIL + NSKP + NRES + NEND){
      int j = idx - NDIL - NSKP - NRES;
      int m = j >> 8; int k = j & 255;
      endWb[j] = (m < OUTC) ? f2bf(end_w[(size_t)m*256 + k]) : 0;
    } else {
      int j = idx - NDIL - NSKP - NRES - NEND;
      int k = j >> 13; int rem = j & 8191; int oc = rem >> 6; int c = rem & 63;
      startWb[j] = (c < INC) ? f2bf(start_w[((size_t)oc*INC + c)*10 + k]) : 0;
    }
  }
}

// ---------------------------------------------------------------------------
// cbias[l][b][m] = dil_b[o(m)] + cond_b[l][o(m)] + sum_c cond_w[l][o(m)][c]*cond[b][c]
// cend[b][o]    = cend_b[o]    + sum_c cend_w[o][c]   * cond[b][c]
__global__ void prep_bias(const float* __restrict__ cond, const float* __restrict__ dil_b,
                          const float* __restrict__ cond_w, const float* __restrict__ cond_b,
                          const float* __restrict__ cend_w, const float* __restrict__ cend_b,
                          float* __restrict__ cbias, float* __restrict__ cend){
  int blk = blockIdx.x; int m = threadIdx.x;
  if (blk < NLAYERS*NB){
    int l = blk >> 2, b = blk & 3;
    int o = ((m & 1) << 7) + (m >> 1);
    float acc = dil_b[l*256 + o] + cond_b[l*256 + o];
    const float* w = cond_w + ((size_t)l*256 + o)*CONDC;
    const float* cv = cond + b*CONDC;
    for (int c = 0; c < CONDC; ++c) acc += w[c]*cv[c];
    cbias[((size_t)l*NB + b)*256 + m] = acc;
  } else {
    int b = blk - NLAYERS*NB;
    float acc = cend_b[m];
    const float* w = cend_w + (size_t)m*CONDC;
    const float* cv = cond + b*CONDC;
    for (int c = 0; c < CONDC; ++c) acc += w[c]*cv[c];
    cend[b*256 + m] = acc;
  }
}

// ---------------------------------------------------------------------------
// start conv via MFMA, tap-decomposed: out[oc][t] = b[oc] + sum_k Wk @ in[:, t+k]
__global__ __launch_bounds__(BLK) void start_mfma(const float* __restrict__ in,
    const unsigned short* __restrict__ startWb, const float* __restrict__ bias,
    float* __restrict__ xout){
  __shared__ char Bs[80*128];   // [tt:80][c:64] bf16, 16B slots: slot ^= (tt&7)
  const int tid = threadIdx.x;
  const int b = blockIdx.y; const int t0 = blockIdx.x * TILE;
  const int lane = tid & 63;
  const int wave = __builtin_amdgcn_readfirstlane(tid >> 6);
  const int q = lane >> 4, r16 = lane & 15;

  #pragma unroll
  for (int i = 0; i < 5; ++i){
    int j = tid + i*BLK;              // 0..2559 = 32 c-pairs x 80 tt
    int c2 = j / 80, tt = j % 80;
    int c = 2*c2; int gt = t0 + tt;
    float v0 = 0.f, v1 = 0.f;
    if (gt < T_IN && c < INC){
      const float* base = in + ((size_t)(b*INC + c))*T_IN + gt;
      v0 = base[0]; v1 = base[T_IN];
    }
    unsigned u = (unsigned)f2bf(v0) | ((unsigned)f2bf(v1) << 16);
    int slot = c2 >> 2;
    *(unsigned*)(Bs + tt*128 + ((((slot ^ (tt & 7)) << 4)) | ((4*c2) & 15))) = u;
  }
  __syncthreads();

  f32x4 acc[4] = {};
  for (int k = 0; k < 10; ++k){
    const unsigned short* A = startWb + ((size_t)k*128 + wave*16)*64;
    #pragma unroll
    for (int kk = 0; kk < 2; ++kk){
      int k0 = kk*32 + q*8;
      bf16x8 a = *(const bf16x8*)(A + (size_t)r16*64 + k0);
      int slot = k0 >> 3;
      #pragma unroll
      for (int nt = 0; nt < 4; ++nt){
        int t = nt*16 + r16 + k;
        bf16x8 bf = *(const bf16x8*)(Bs + t*128 + ((slot ^ (t & 7)) << 4));
        acc[nt] = __builtin_amdgcn_mfma_f32_16x16x32_bf16(a, bf, acc[nt], 0, 0, 0);
      }
    }
  }
  const float* bb = bias + wave*16;
  #pragma unroll
  for (int nt = 0; nt < 4; ++nt){
    int gt = t0 + nt*16 + r16;
    if (gt < T0LEN){
      #pragma unroll
      for (int rr = 0; rr < 4; ++rr){
        int oc = wave*16 + 4*q + rr;
        xout[(size_t)(b*RES_C + oc)*T_IN + gt] = acc[nt][rr] + bb[4*q + rr];
      }
    }
  }
}

// ---------------------------------------------------------------------------
// Fused MFMA layer (R5-proven conventions; LTILE=32 for 2x grid parallelism).
__global__ __launch_bounds__(BLK) void layer_mfma(
    const float* __restrict__ xin, float* __restrict__ xout, float* __restrict__ skip,
    const unsigned short* __restrict__ dilWb, const unsigned short* __restrict__ skipWb,
    const unsigned short* __restrict__ resWb, const float* __restrict__ cbias,
    const float* __restrict__ skip_b, const float* __restrict__ res_b,
    int layer, int d, int Tin, int Tout, int first, int last){
  __shared__ char Bx[LTILE*512];   // [t][k:256] bf16, 16B slots swizzled: slot ^= (t&31)
  __shared__ char Bz[LTILE*256];   // [t][ch:128] bf16, slot ^= (t&15)
  const int tid = threadIdx.x;
  const int b = blockIdx.y; const int t0 = blockIdx.x*LTILE;
  const int lane = tid & 63;
  const int wave = __builtin_amdgcn_readfirstlane(tid >> 6);
  const int q = lane >> 4;          // 0..3
  const int r16 = lane & 15;        // row-in-Afrag / col-in-Bfrag

  // ---- stage Bx: k<128 = x[t] ch k ; k>=128 = x[t+d] ch k-128
  // 64 lanes = 32 t-values x 2 k-halves; wave covers 32 k-channels.
  {
    const int t = lane & 31;
    const int kh = lane >> 5;       // 0/1
    const int gt = t0 + t;
    #pragma unroll
    for (int i = 0; i < 16; i += 2){
      int k0 = wave*32 + kh*16 + i;
      int tap = k0 >> 7; int c = k0 & 127;
      int gtt = gt + (tap ? d : 0);
      float v0 = 0.f, v1 = 0.f;
      if (gtt < Tin){
        const float* base = xin + ((size_t)(b*RES_C + c))*T_IN + gtt;
        v0 = base[0]; v1 = base[T_IN];
      }
      unsigned u = (unsigned)f2bf(v0) | ((unsigned)f2bf(v1) << 16);
      int slot = k0 >> 3;
      *(unsigned*)(Bx + t*512 + ((slot ^ (t & 31)) << 4) + ((2*k0) & 15)) = u;
    }
  }
  __syncthreads();

  // ---- dilated GEMM: M=256 (f/g interleaved), K=256, N=32. wave owns 32 rows.
  f32x4 acc[2][2] = {};
  {
    const unsigned short* A = dilWb + (size_t)layer*256*256 + (size_t)(wave*32)*256;
    for (int kk = 0; kk < 8; ++kk){
      int k0 = kk*32 + q*8;
      bf16x8 a0 = *(const bf16x8*)(A + (size_t)r16*256 + k0);
      bf16x8 a1 = *(const bf16x8*)(A + (size_t)(16 + r16)*256 + k0);
      int slot = k0 >> 3;
      #pragma unroll
      for (int nt = 0; nt < 2; ++nt){
        int t = nt*16 + r16;
        bf16x8 bf = *(const bf16x8*)(Bx + t*512 + ((slot ^ (t & 31)) << 4));
        acc[0][nt] = __builtin_amdgcn_mfma_f32_16x16x32_bf16(a0, bf, acc[0][nt], 0, 0, 0);
        acc[1][nt] = __builtin_amdgcn_mfma_f32_16x16x32_bf16(a1, bf, acc[1][nt], 0, 0, 0);
      }
    }
  }

  // ---- gate + write z to Bz (rows 4q+r hold f,g,f,g of channels 2q,2q+1)
  {
    const float* cb = cbias + ((size_t)layer*NB + b)*256 + wave*32;
    #pragma unroll
    for (int mt = 0; mt < 2; ++mt){
      float bf0 = cb[mt*16 + 4*q + 0];
      float bg0 = cb[mt*16 + 4*q + 1];
      float bf1 = cb[mt*16 + 4*q + 2];
      float bg1 = cb[mt*16 + 4*q + 3];
      int ch0 = wave*16 + mt*8 + 2*q;
      int slot = ch0 >> 3;
      #pragma unroll
      for (int nt = 0; nt < 2; ++nt){
        float z0 = ftanh(acc[mt][nt][0] + bf0) * fsigmoid(acc[mt][nt][1] + bg0);
        float z1 = ftanh(acc[mt][nt][2] + bf1) * fsigmoid(acc[mt][nt][3] + bg1);
        int t = nt*16 + r16;
        unsigned u = (unsigned)f2bf(z0) | ((unsigned)f2bf(z1) << 16);
        *(unsigned*)(Bz + t*256 + ((slot ^ (t & 15)) << 4) + ((2*ch0) & 15)) = u;
      }
    }
  }
  __syncthreads();

  // ---- skip GEMM: M=256, K=128. wave owns 32 rows.
  {
    f32x4 sacc[2][2] = {};
    const unsigned short* A = skipWb + (size_t)layer*256*128 + (size_t)(wave*32)*128;
    for (int kk = 0; kk < 4; ++kk){
      int k0 = kk*32 + q*8;
      bf16x8 a0 = *(const bf16x8*)(A + (size_t)r16*128 + k0);
      bf16x8 a1 = *(const bf16x8*)(A + (size_t)(16 + r16)*128 + k0);
      int slot = k0 >> 3;
      #pragma unroll
      for (int nt = 0; nt < 2; ++nt){
        int t = nt*16 + r16;
        bf16x8 bf = *(const bf16x8*)(Bz + t*256 + ((slot ^ (t & 15)) << 4));
        sacc[0][nt] = __builtin_amdgcn_mfma_f32_16x16x32_bf16(a0, bf, sacc[0][nt], 0, 0, 0);
        sacc[1][nt] = __builtin_amdgcn_mfma_f32_16x16x32_bf16(a1, bf, sacc[1][nt], 0, 0, 0);
      }
    }
    const float* sb = skip_b + layer*256 + wave*32;
    const int woff = Tout - T_FIN;
    #pragma unroll
    for (int mt = 0; mt < 2; ++mt){
      #pragma unroll
      for (int nt = 0; nt < 2; ++nt){
        int gt = t0 + nt*16 + r16;
        int tw = gt - woff;
        if (gt < Tout && tw >= 0){
          #pragma unroll
          for (int rr = 0; rr < 4; ++rr){
            int m = wave*32 + mt*16 + 4*q + rr;
            size_t si = ((size_t)(b*SKIPC + m))*T_FIN + tw;
            float v = sacc[mt][nt][rr] + sb[mt*16 + 4*q + rr];
            skip[si] = first ? v : (skip[si] + v);
          }
        }
      }
    }
  }

  // ---- res GEMM: M=128, K=128. wave owns 16 rows. (skipped on last layer)
  if (!last){
    f32x4 racc[2] = {};
    const unsigned short* A = resWb + (size_t)layer*128*128 + (size_t)(wave*16)*128;
    for (int kk = 0; kk < 4; ++kk){
      int k0 = kk*32 + q*8;
      bf16x8 a0 = *(const bf16x8*)(A + (size_t)r16*128 + k0);
      int slot = k0 >> 3;
      #pragma unroll
      for (int nt = 0; nt < 2; ++nt){
        int t = nt*16 + r16;
        bf16x8 bf = *(const bf16x8*)(Bz + t*256 + ((slot ^ (t & 15)) << 4));
        racc[nt] = __builtin_amdgcn_mfma_f32_16x16x32_bf16(a0, bf, racc[nt], 0, 0, 0);
      }
    }
    const float* rb = res_b + layer*RES_C + wave*16;
    #pragma unroll
    for (int nt = 0; nt < 2; ++nt){
      int gt = t0 + nt*16 + r16;
      if (gt < Tout){
        #pragma unroll
        for (int rr = 0; rr < 4; ++rr){
          int m = wave*16 + 4*q + rr;
          size_t base = ((size_t)(b*RES_C + m))*T_IN;
          xout[base + gt] = racc[nt][rr] + rb[4*q + rr] + xin[base + gt + d];
        }
      }
    }
  }
}

// ---------------------------------------------------------------------------
// final (R5-proven): out = sigmoid(end_b + endW @ tanh(skip + cend)), M=240(pad 256), K=256
__global__ __launch_bounds__(BLK) void final_mfma(const float* __restrict__ skip,
    const float* __restrict__ cend, const unsigned short* __restrict__ endWb,
    const float* __restrict__ end_b, float* __restrict__ out){
  __shared__ char Bs[64*512];   // [t][s:256] bf16, slot ^= (t&31)
  const int tid = threadIdx.x;
  const int b = blockIdx.y; const int t0 = blockIdx.x*TILE;
  const int lane = tid & 63;
  const int wave = __builtin_amdgcn_readfirstlane(tid >> 6);
  const int q = lane >> 4;
  const int r16 = lane & 15;

  {
    const int t = lane;
    const int gt = t0 + t;
    #pragma unroll
    for (int i = 0; i < 32; i += 2){
      int s0 = wave*32 + i;
      float v0 = 0.f, v1 = 0.f;
      if (gt < T_FIN){
        const float* base = skip + ((size_t)(b*SKIPC + s0))*T_FIN + gt;
        v0 = ftanh(base[0]     + cend[b*256 + s0]);
        v1 = ftanh(base[T_FIN] + cend[b*256 + s0 + 1]);
      }
      unsigned u = (unsigned)f2bf(v0) | ((unsigned)f2bf(v1) << 16);
      int slot = s0 >> 3;
      *(unsigned*)(Bs + t*512 + ((slot ^ (t & 31)) << 4) + ((2*s0) & 15)) = u;
    }
  }
  __syncthreads();

  f32x4 acc[2][4] = {};
  const unsigned short* A = endWb + (size_t)(wave*32)*256;
  for (int kk = 0; kk < 8; ++kk){
    int k0 = kk*32 + q*8;
    bf16x8 a0 = *(const bf16x8*)(A + (size_t)r16*256 + k0);
    bf16x8 a1 = *(const bf16x8*)(A + (size_t)(16 + r16)*256 + k0);
    int slot = k0 >> 3;
    #pragma unroll
    for (int nt = 0; nt < 4; ++nt){
      int t = nt*16 + r16;
      bf16x8 bf = *(const bf16x8*)(Bs + t*512 + ((slot ^ (t & 31)) << 4));
      acc[0][nt] = __builtin_amdgcn_mfma_f32_16x16x32_bf16(a0, bf, acc[0][nt], 0, 0, 0);
      acc[1][nt] = __builtin_amdgcn_mfma_f32_16x16x32_bf16(a1, bf, acc[1][nt], 0, 0, 0);
    }
  }
  #pragma unroll
  for (int mt = 0; mt < 2; ++mt){
    #pragma unroll
    for (int nt = 0; nt < 4; ++nt){
      int gt = t0 + nt*16 + r16;
      if (gt < T_FIN){
        #pragma unroll
        for (int rr = 0; rr < 4; ++rr){
          int m = wave*32 + mt*16 + 4*q + rr;
          if (m < OUTC)
            out[((size_t)(b*OUTC + m))*T_FIN + gt] = fsigmoid(acc[mt][nt][rr] + end_b[m]);
        }
      }
    }
  }
}

// ---------------------------------------------------------------------------
extern "C" void kernel_launch(void* const* d_in, const int* in_sizes, int n_in,
                              void* d_out, int out_size, void* d_ws, size_t ws_size,
                              hipStream_t stream){
  const float* input     = (const float*)d_in[0];
  const float* condition = (const float*)d_in[1];
  const float* start_w   = (const float*)d_in[2];
  const float* start_b   = (const float*)d_in[3];
  const float* dil_w     = (const float*)d_in[4];
  const float* dil_b     = (const float*)d_in[5];
  const float* cond_w    = (const float*)d_in[6];
  const float* cond_b    = (const float*)d_in[7];
  const float* res_w     = (const float*)d_in[8];
  const float* res_b     = (const float*)d_in[9];
  const float* skip_w    = (const float*)d_in[10];
  const float* skip_b    = (const float*)d_in[11];
  const float* end_w     = (const float*)d_in[12];
  const float* end_b     = (const float*)d_in[13];
  const float* cend_w    = (const float*)d_in[14];
  const float* cend_b    = (const float*)d_in[15];
  float* out = (float*)d_out;

  char* ws = (char*)d_ws;
  size_t off = 0;
  auto carve = [&](size_t bytes) -> char* {
    char* p = ws + off; off = (off + bytes + 255) & ~(size_t)255; return p;
  };
  float* xA   = (float*)carve((size_t)NB*RES_C*T_IN*4);
  float* xB   = (float*)carve((size_t)NB*RES_C*T_IN*4);
  float* skip = (float*)carve((size_t)NB*SKIPC*T_FIN*4);
  unsigned short* dilWb   = (unsigned short*)carve((size_t)NDIL*2);
  unsigned short* skipWb  = (unsigned short*)carve((size_t)NSKP*2);
  unsigned short* resWb   = (unsigned short*)carve((size_t)NRES*2);
  unsigned short* endWb   = (unsigned short*)carve((size_t)NEND*2);
  unsigned short* startWb = (unsigned short*)carve((size_t)NSTART*2);
  float* cbias = (float*)carve((size_t)NLAYERS*NB*256*4);
  float* cend  = (float*)carve((size_t)NB*256*4);

  prep_weights<<<2048, 256, 0, stream>>>(dil_w, skip_w, res_w, end_w, start_w,
                                         dilWb, skipWb, resWb, endWb, startWb);
  prep_bias<<<NLAYERS*NB + NB, 256, 0, stream>>>(condition, dil_b, cond_w, cond_b,
                                                 cend_w, cend_b, cbias, cend);

  {
    dim3 grid((T0LEN + TILE - 1)/TILE, NB);
    start_mfma<<<grid, BLK, 0, stream>>>(input, startWb, start_b, xA);
  }

  int dils[NLAYERS]; int n = 0;
  for (int bb = 0; bb < 2; ++bb){ int nn = (bb==0) ? 10 : 9; for (int k = 0; k < nn; ++k) dils[n++] = 1<<k; }

  float* xin = xA; float* xo = xB;
  int Tin = T0LEN;
  for (int i = 0; i < NLAYERS; ++i){
    int d = dils[i]; int Tout = Tin - d;
    dim3 grid((Tout + LTILE - 1)/LTILE, NB);
    layer_mfma<<<grid, BLK, 0, stream>>>(xin, xo, skip, dilWb, skipWb, resWb, cbias,
                                         skip_b, res_b, i, d, Tin, Tout,
                                         (i==0)?1:0, (i==NLAYERS-1)?1:0);
    float* tmp = xin; xin = xo; xo = tmp;
    Tin = Tout;
  }

  {
    dim3 grid((T_FIN + TILE - 1)/TILE, NB);
    final_mfma<<<grid, BLK, 0, stream>>>(skip, cend, endWb, end_b, out);
  }
}